// Round 10
// baseline (180.781 us; speedup 1.0000x reference)
//
#include <hip/hip_runtime.h>
#include <stdint.h>

#define SEQ    512
#define BATCH  1024
#define NTAG   54
#define TSTART 52
#define TSTOP  53
#define EMROW  (BATCH * NTAG)   // 55296 floats per timestep

// ---------------------------------------------------------------------------
// Linear-space CRF forward, 2 batch elements per wave (packed rows).
// Lane 32h+l (l<27) holds rows (2l,2l+1) of batch b0+h as a float pair.
//   u[j] = exp(alpha[j] - esum*ln2)
//   step: u' = (sum_i E[j,i]*u[i]) * (exp(feat[j]) * 2^-e_lag)
// DS per wave per step: 1 ds_write_b64 + 14 broadcast ds_read_b128 + 1
// ds_read_b64 = 16 instr; 2 waves/CU -> 32 DS instr/CU (round 8: 64 = wall).
//
// Round-10 fixes vs the NaN round:
//  (1) no imm-offset on global_load_lds: second stage uses gp+54 pointer
//      arithmetic (the 216-byte imm was the only unexercised mechanism and
//      the prime suspect for uninit LDS -> exp(junk)=Inf -> 0*Inf=NaN).
//  (2) pad lanes (l31>=27) never update u (upL_ && live) -> u stays 0, so
//      no non-finite value can ever enter alds regardless of staged bytes.
// ---------------------------------------------------------------------------

typedef const __attribute__((address_space(1))) void* gld_gptr;
typedef __attribute__((address_space(3))) void*       gld_lptr;

__device__ __forceinline__ void stage4(const float* g, float* l) {
    __builtin_amdgcn_global_load_lds((gld_gptr)g, (gld_lptr)l, 4, 0, 0);
}

#define STEP(o, INC) do {                                                     \
    float* sl_ = (float*)&flds[((o) + 8) & 15][0][0];                         \
    stage4(gp,      sl_);                                                     \
    stage4(gp + 54, sl_ + 64);                                                \
    gp += (INC);                                                              \
    asm volatile("s_waitcnt vmcnt(16)" ::: "memory");                         \
    *(float2*)&alds[half][rowb] = make_float2(u2x, u2y);                      \
    float2 fv_ = *(const float2*)&flds[(o)][half][rowb];                      \
    float sc_  = __uint_as_float((unsigned)(127 - e_lagv) << 23);             \
    float efx_ = __expf(fv_.x) * sc_;                                         \
    float efy_ = __expf(fv_.y) * sc_;                                         \
    float aX0=0.f,aX1=0.f,aX2=0.f,aX3=0.f;                                    \
    float aY0=0.f,aY1=0.f,aY2=0.f,aY3=0.f;                                    \
    const float4* up_ = (const float4*)&alds[half][0];                        \
    _Pragma("unroll")                                                         \
    for (int g_ = 0; g_ < 14; ++g_) {                                         \
        float4 uv_ = up_[g_];                                                 \
        aX0 = fmaf(EX[4*g_+0], uv_.x, aX0);                                   \
        aY0 = fmaf(EY[4*g_+0], uv_.x, aY0);                                   \
        aX1 = fmaf(EX[4*g_+1], uv_.y, aX1);                                   \
        aY1 = fmaf(EY[4*g_+1], uv_.y, aY1);                                   \
        aX2 = fmaf(EX[4*g_+2], uv_.z, aX2);                                   \
        aY2 = fmaf(EY[4*g_+2], uv_.z, aY2);                                   \
        aX3 = fmaf(EX[4*g_+3], uv_.w, aX3);                                   \
        aY3 = fmaf(EY[4*g_+3], uv_.w, aY3);                                   \
    }                                                                         \
    float unx_ = ((aX0+aX1)+(aX2+aX3)) * efx_;                                \
    float uny_ = ((aY0+aY1)+(aY2+aY3)) * efy_;                                \
    bool upA_ = (curA & 1ull) != 0ull;                                        \
    bool upB_ = (curB & 1ull) != 0ull;                                        \
    bool upL_ = (half ? upB_ : upA_) && live;                                 \
    u2x = upL_ ? unx_ : u2x;                                                  \
    u2y = upL_ ? uny_ : u2y;                                                  \
    esum += upL_ ? e_lagv : 0;                                                \
    curA >>= 1; curB >>= 1;                                                   \
    int bA_ = __builtin_amdgcn_readlane(__float_as_int(u2x), 0);              \
    int bB_ = __builtin_amdgcn_readlane(__float_as_int(u2x), 32);             \
    int eA_ = (((bA_ >> 23) & 255) - 127);                                    \
    eA_ = eA_ < -40 ? -40 : (eA_ > 40 ? 40 : eA_);                            \
    int eB_ = (((bB_ >> 23) & 255) - 127);                                    \
    eB_ = eB_ < -40 ? -40 : (eB_ > 40 ? 40 : eB_);                            \
    e_lagv = half ? eB_ : eA_;                                                \
} while (0)

__global__ __launch_bounds__(64, 1) void crf_fwd_kernel(
    const float* __restrict__ em, const float* __restrict__ tr,
    const int* __restrict__ tags, const int* __restrict__ mask,
    float* __restrict__ part, int* __restrict__ msum)
{
    __shared__ float tlds[NTAG * NTAG];
    __shared__ __align__(16) float alds[2][64];       // u vectors, A and B
    __shared__ __align__(16) float flds[16][2][64];   // emission staging ring

    const int lane = threadIdx.x;     // 64-thread block = 1 wave
    for (int k = lane; k < NTAG * NTAG; k += 64) tlds[k] = tr[k];
    __syncthreads();

    const int  b0   = blockIdx.x * 2;
    const bool half = lane >= 32;
    const int  l31  = lane & 31;
    const int  rowb = 2 * l31;        // rows (rowb, rowb+1); l31>=27 = pad
    const bool live = l31 < 27;

    // --- E rows (two per lane), exp'd, zero-padded to 56, pinned ---
    float EX[56], EY[56];
    #pragma unroll
    for (int i = 0; i < 56; ++i) {
        EX[i] = (live && i < NTAG) ? __expf(tlds[(rowb    ) * NTAG + i]) : 0.f;
        EY[i] = (live && i < NTAG) ? __expf(tlds[(rowb + 1) * NTAG + i]) : 0.f;
        asm("" : "+v"(EX[i]));
        asm("" : "+v"(EY[i]));
    }
    float esx = live ? __expf(tlds[TSTOP * NTAG + rowb    ]) : 0.f;
    float esy = live ? __expf(tlds[TSTOP * NTAG + rowb + 1]) : 0.f;

    // =======================================================================
    // Prepass: gold + mask ballots for BOTH batch elements
    // =======================================================================
    float    gold2[2] = {0.f, 0.f};
    int      ms2[2]   = {0, 0};
    uint64_t BA[8], BB[8];
    #pragma unroll
    for (int h = 0; h < 2; ++h) {
        const int b2 = b0 + h;
        #pragma unroll
        for (int r = 0; r < 8; ++r) {
            int s  = r * 64 + lane;
            int tg = tags[s * BATCH + b2];
            int mk = mask[s * BATCH + b2];
            int tp = (s == 0) ? TSTART : tags[(s - 1) * BATCH + b2];
            float emv = em[(size_t)s * EMROW + (size_t)b2 * NTAG + tg];
            float trv = tlds[tg * NTAG + tp];
            float mf  = (s == 0) ? 1.f : (float)mk;
            gold2[h] = fmaf(trv + emv, mf, gold2[h]);
            ms2[h] += mk;
            uint64_t bl = __ballot(mk > 0);
            if (h == 0) BA[r] = bl; else BB[r] = bl;
        }
    }
    #pragma unroll
    for (int off = 32; off >= 1; off >>= 1) {
        gold2[0] += __shfl_xor(gold2[0], off);
        gold2[1] += __shfl_xor(gold2[1], off);
        ms2[0]   += __shfl_xor(ms2[0], off);
        ms2[1]   += __shfl_xor(ms2[1], off);
    }

    // =======================================================================
    // Serial forward recursion
    // =======================================================================
    float u2x = (l31 == TSTART / 2) ? 1.f : 0.f;   // row 52 lives in lane 26 .x
    float u2y = 0.f;
    int   esum   = 0;
    int   e_lagv = 0;

    asm volatile("s_waitcnt vmcnt(0)" ::: "memory");   // drain prepass VMEM

    // per-lane global src: row index = lane (clamped); batch b0; step 0
    const float* gp = em + (size_t)b0 * NTAG + (lane < NTAG ? lane : NTAG - 1);
    #pragma unroll
    for (int s = 0; s < 8; ++s) {      // prologue: stage steps 0..7 (16 ops)
        float* sl = (float*)&flds[s][0][0];
        stage4(gp,      sl);
        stage4(gp + 54, sl + 64);
        gp += EMROW;
    }                                   // gp -> step 8

    for (int c = 0; c < 8; ++c) {
        uint64_t curA = BA[0], curB = BB[0];
        for (int q = 0; q < 4; ++q) {
            const size_t incB = (c == 7 && q == 3) ? 0 : (size_t)EMROW;
            STEP( 0, EMROW); STEP( 1, EMROW); STEP( 2, EMROW); STEP( 3, EMROW);
            STEP( 4, EMROW); STEP( 5, EMROW); STEP( 6, EMROW); STEP( 7, incB);
            STEP( 8, incB);  STEP( 9, incB);  STEP(10, incB);  STEP(11, incB);
            STEP(12, incB);  STEP(13, incB);  STEP(14, incB);  STEP(15, incB);
        }
        #pragma unroll
        for (int r = 0; r < 7; ++r) { BA[r] = BA[r + 1]; BB[r] = BB[r + 1]; }
    }

    // --- final forward score per half ---
    float us = u2x * esx + u2y * esy;
    #pragma unroll
    for (int off = 16; off >= 1; off >>= 1) us += __shfl_xor(us, off);
    float fwd = __logf(us) + (float)esum * 0.69314718f;

    asm volatile("s_waitcnt vmcnt(0)" ::: "memory");   // clean counter state
    int   myb = half ? b0 + 1 : b0;
    int   mym = half ? ms2[1] : ms2[0];
    float myg = half ? gold2[1] : gold2[0];
    int li    = (mym > 0) ? (mym - 1) : 0;
    int ltag  = tags[li * BATCH + myb];
    myg += tlds[TSTOP * NTAG + ltag];

    if (l31 == 0) { part[myb] = fwd - myg; msum[myb] = mym; }
}

// ---------------------------------------------------------------------------
// Kernel 2: deterministic reduction  out = sum(part) / sum(msum)
// ---------------------------------------------------------------------------
__global__ __launch_bounds__(256) void crf_reduce_kernel(
    const float* __restrict__ part, const int* __restrict__ msum,
    float* __restrict__ out)
{
    const int tid = threadIdx.x;
    float s = 0.f;
    int   m = 0;
    for (int k = tid; k < BATCH; k += 256) { s += part[k]; m += msum[k]; }
    #pragma unroll
    for (int off = 32; off >= 1; off >>= 1) {
        s += __shfl_xor(s, off);
        m += __shfl_xor(m, off);
    }
    __shared__ float sl[4];
    __shared__ int   ml[4];
    if ((tid & 63) == 0) { sl[tid >> 6] = s; ml[tid >> 6] = m; }
    __syncthreads();
    if (tid == 0)
        out[0] = (sl[0] + sl[1] + sl[2] + sl[3]) /
                 (float)(ml[0] + ml[1] + ml[2] + ml[3]);
}

extern "C" void kernel_launch(void* const* d_in, const int* in_sizes, int n_in,
                              void* d_out, int out_size, void* d_ws, size_t ws_size,
                              hipStream_t stream)
{
    const float* em   = (const float*)d_in[0];
    const float* tr   = (const float*)d_in[1];
    const int*   tags = (const int*)d_in[2];
    const int*   mask = (const int*)d_in[3];

    float* part  = (float*)d_ws;
    int*   msumw = (int*)((char*)d_ws + BATCH * sizeof(float));
    float* out   = (float*)d_out;

    crf_fwd_kernel<<<BATCH / 2, 64, 0, stream>>>(em, tr, tags, mask, part, msumw);
    crf_reduce_kernel<<<1, 256, 0, stream>>>(part, msumw, out);
}